// Round 6
// baseline (8524.929 us; speedup 1.0000x reference)
//
#include <hip/hip_runtime.h>

// LSTM fused persistent kernel for MI355X — round 6 (R4 math + sleepy poll + XCD swizzle).
// 16 groups x 16 CUs; CU owns 32 hidden units (128 gate-cols), Wh fp16 in VGPRs.
// Cross-CU h exchange per step via LLC (sc1) with NARROW dataflow polling:
// wave wv stages chunks 4wv..4wv+3 and polls ONLY their 16 producer tags
// (one 64B line), with s_sleep(1) backoff in the retry path. Lag bound D=2
// (poll transitivity) -> triple-buffered global h, double-buffered LDS,
// one __syncthreads per step.

typedef __attribute__((ext_vector_type(8))) _Float16 f16x8;
typedef __attribute__((ext_vector_type(4))) float f32x4;

#define NTHR 256
constexpr int T_LEN = 512, EMB = 1024, HID = 512, NCLS = 10;
constexpr int GSIZE = 16;   // CUs per group
constexpr int NGRP  = 16;   // groups
constexpr int BPG   = 16;   // batches per group
constexpr int UPC   = 32;   // hidden units per CU
constexpr int COLS_PC = 128;
constexpr int NKT = 16;     // K tiles of 32 (HID=512)

__device__ __forceinline__ float sigmf(float x)    { return 1.f / (1.f + __expf(-x)); }
__device__ __forceinline__ float tanhfast(float x) { return 1.f - 2.f / (__expf(2.f * x) + 1.f); }

__global__ __launch_bounds__(NTHR, 1) void lstm_fused(
    const int* __restrict__ xtok, const float* __restrict__ emb,
    const float* __restrict__ Wgx, const float* __restrict__ Wgh, const float* __restrict__ b_g,
    const float* __restrict__ Wix, const float* __restrict__ Wih, const float* __restrict__ b_i,
    const float* __restrict__ Wfx, const float* __restrict__ Wfh, const float* __restrict__ b_f,
    const float* __restrict__ Wox, const float* __restrict__ Woh, const float* __restrict__ b_o,
    const float* __restrict__ Wph, const float* __restrict__ b_p,
    float* __restrict__ out, unsigned* __restrict__ tags, _Float16* __restrict__ hbuf)
{
  const int tid  = threadIdx.x;
  const int wv   = tid >> 6;     // wave 0..3
  const int lane = tid & 63;
  const int q    = lane >> 4;    // lane quarter
  const int c    = lane & 15;
  const int wg   = blockIdx.x;
  // XCD-aware bijective relabel: group = {b7, b2b1b0}, cu = {b6..b3}.
  // All 16 WGs of a group share wg%8 -> same XCD under i%8 round-robin.
  const int grp  = (wg & 7) | ((wg >> 7) << 3);
  const int cu   = (wg >> 3) & 15;

  __shared__ __align__(16) _Float16 h_lds[2][BPG * HID];  // 2 x 16 KB, chunk-major
  __shared__ __align__(16) _Float16 hstw[4][128];         // per-wave pack staging
  __shared__ unsigned char xl[BPG][T_LEN];                // 8 KB packed tokens
  __shared__ float projl[3][COLS_PC];                     // 1.5 KB
  __shared__ float projp[3][COLS_PC];                     // 1.5 KB partials

  // ---- pack this group's tokens into LDS (u8)
  for (int idx = tid; idx < BPG * T_LEN; idx += NTHR) {
    int bl = idx >> 9, tt = idx & (T_LEN - 1);
    xl[bl][tt] = (unsigned char)xtok[(grp * BPG + bl) * T_LEN + tt];
  }

  // ---- proj[v][cc] = b_gate[j] + emb[v] . Wx[:,gate,j], split over 2 halves of e
  {
    int cc = tid & 127, half = tid >> 7;
    int w2 = cc >> 5, nt = (cc >> 4) & 1, c2 = cc & 15;
    int gate = nt * 2 + (c2 >> 3);
    int j = cu * UPC + w2 * 8 + (c2 & 7);
    const float* Wx = gate == 0 ? Wgx : gate == 1 ? Wix : gate == 2 ? Wfx : Wox;
    const float* bb = gate == 0 ? b_g : gate == 1 ? b_i : gate == 2 ? b_f : b_o;
    int e0 = half * (EMB / 2);
    for (int v = 0; v < 3; ++v) {
      float s = half ? 0.f : bb[j];
      const float* er = emb + v * EMB + e0;
      const float* wp = Wx + e0 * HID + j;
      #pragma unroll 4
      for (int e = 0; e < EMB / 2; ++e) s = fmaf(er[e], wp[e * HID], s);
      (half ? projp : projl)[v][cc] = s;
    }
  }
  __syncthreads();
  for (int idx = tid; idx < 3 * COLS_PC; idx += NTHR) {
    int v = idx >> 7, cc = idx & 127;
    projl[v][cc] += projp[v][cc];
  }

  // ---- Wh B-fragments into registers (fp32 -> fp16), kept for all 512 steps.
  // (q, jj) -> k = 8q + jj, applied identically to A and B (HW perm cancels).
  f16x8 Bf[2][NKT];
  {
    int g0 = c >> 3;
    int j = cu * UPC + wv * 8 + (c & 7);
    #pragma unroll
    for (int nt = 0; nt < 2; ++nt) {
      int gate = nt * 2 + g0;
      const float* W = gate == 0 ? Wgh : gate == 1 ? Wih : gate == 2 ? Wfh : Woh;
      #pragma unroll
      for (int kt = 0; kt < NKT; ++kt) {
        f16x8 tmp;
        #pragma unroll
        for (int jj = 0; jj < 8; ++jj)
          tmp[jj] = (_Float16)W[(kt * 32 + q * 8 + jj) * HID + j];
        Bf[nt][kt] = tmp;
      }
    }
  }

  float cst[4] = {0.f, 0.f, 0.f, 0.f};     // c-state, rows q*4+r
  unsigned* tg = tags + grp * 64;          // 64 per-wave tags; line wv = its producers
  unsigned* hb32 = (unsigned*)hbuf;
  unsigned long long* hb64 = (unsigned long long*)hbuf;
  const int gq3 = grp * 3 * 2048;          // group base, qwords (3 bufs x 2048)
  const int gd3 = grp * 3 * 4096;          // group base, dwords
  int bufr = 0;                            // == t % 3
  __syncthreads();

  for (int t = 0; t < T_LEN; ++t) {
    const int pl = t & 1;
    if (t > 0) {
      // ---- narrow poll with backoff: my 16 producers (CUs 4wv..4wv+3) >= t.
      // tag>=t implies (transitively) all group waves >= t-1, so the buffer
      // we will overwrite at distance 3 has been fully consumed, and the
      // chunks we read were fully published.
      const unsigned tcmp = (unsigned)t;
      const unsigned* myline = tg + wv * 16;
      for (;;) {
        unsigned tv = __hip_atomic_load(myline + (lane & 15), __ATOMIC_RELAXED, __HIP_MEMORY_SCOPE_AGENT);
        if (__all((int)(tv >= tcmp))) break;
        __builtin_amdgcn_s_sleep(1);
      }
      asm volatile("" ::: "memory");
      // ---- stage chunks kt = wv*4 .. wv*4+3 into LDS (chunk layout == A-frag)
      const int pbase = gq3 + bufr * 2048;
      #pragma unroll
      for (int i = 0; i < 4; ++i) {
        int kt = wv * 4 + i;
        int o = pbase + kt * 128 + lane * 2;
        unsigned long long d0 = __hip_atomic_load(hb64 + o,     __ATOMIC_RELAXED, __HIP_MEMORY_SCOPE_AGENT);
        unsigned long long d1 = __hip_atomic_load(hb64 + o + 1, __ATOMIC_RELAXED, __HIP_MEMORY_SCOPE_AGENT);
        unsigned long long* dl = (unsigned long long*)&h_lds[pl][kt * 512 + lane * 8];
        dl[0] = d0; dl[1] = d1;
      }
    }
    __syncthreads();

    // ---- gates tile: 16 batches x 32 cols per wave (2 n-tiles), K=512
    f32x4 acc0 = {0.f, 0.f, 0.f, 0.f}, acc1 = {0.f, 0.f, 0.f, 0.f};
    if (t > 0) {
      const _Float16* hp = h_lds[pl];
      #pragma unroll
      for (int kt = 0; kt < NKT; ++kt) {
        f16x8 a = *(const f16x8*)(hp + kt * 512 + lane * 8);
        acc0 = __builtin_amdgcn_mfma_f32_16x16x32_f16(a, Bf[0][kt], acc0, 0, 0, 0);
        acc1 = __builtin_amdgcn_mfma_f32_16x16x32_f16(a, Bf[1][kt], acc1, 0, 0, 0);
      }
    }

    // ---- nonlinearity + state update. C/D layout: col=lane&15, row=4q+reg.
    bool lo = (c < 8);
    #pragma unroll
    for (int r = 0; r < 4; ++r) {
      int bl = q * 4 + r;                     // batch row in tile
      int v = xl[bl][t];
      float p0 = acc0[r] + projl[v][wv * 32 + c];
      float p1 = acc1[r] + projl[v][wv * 32 + 16 + c];
      float p0x = __shfl_xor(p0, 8);
      float p1x = __shfl_xor(p1, 8);
      float gg = lo ? p0  : p0x;
      float ii = lo ? p0x : p0;
      float ff = lo ? p1  : p1x;
      float oo = lo ? p1x : p1;
      gg = tanhfast(gg); ii = sigmf(ii); ff = sigmf(ff); oo = sigmf(oo);
      float cn = fmaf(cst[r], ff, gg * ii);
      cst[r] = cn;
      float hv = tanhfast(cn) * oo;
      if (lo) hstw[wv][bl * 8 + c] = (_Float16)hv;   // same-wave staging (no barrier)
    }

    // ---- publish this wave's 256B slice into buffer (t+1)%3 + release tag
    int bufw = bufr + 1; if (bufw == 3) bufw = 0;
    unsigned pub = ((const unsigned*)&hstw[wv][0])[lane];
    int po = gd3 + bufw * 4096 + cu * 256 + wv * 64 + lane;
    __hip_atomic_store(hb32 + po, pub, __ATOMIC_RELAXED, __HIP_MEMORY_SCOPE_AGENT);
    if (lane == 0)
      __hip_atomic_store(tg + cu * 4 + wv, (unsigned)(t + 1), __ATOMIC_RELEASE, __HIP_MEMORY_SCOPE_AGENT);
    bufr = bufw;
  }

  // ---- epilogue (R2/R4-proven form): wave0 polls all 64 tags, then computes
  // p = h_T @ W_ph + b_p ; log_softmax for batch grp*16+cu. h_512 in buffer 2.
  if (wv == 0) {
    for (;;) {
      unsigned tv = __hip_atomic_load(tg + lane, __ATOMIC_RELAXED, __HIP_MEMORY_SCOPE_AGENT);
      if (__all((int)(tv >= (unsigned)T_LEN))) break;
      __builtin_amdgcn_s_sleep(1);
    }
    asm volatile("" ::: "memory");
    float pc[NCLS];
    #pragma unroll
    for (int k2 = 0; k2 < NCLS; ++k2) pc[k2] = 0.f;
    int kt = lane >> 2, qa = lane & 3;        // each lane: 8 consecutive j
    const unsigned long long* hs = hb64 + gq3 + 2 * 2048 + (kt * 64 + qa * 16 + cu) * 2;
    unsigned long long d0 = __hip_atomic_load(hs,     __ATOMIC_RELAXED, __HIP_MEMORY_SCOPE_AGENT);
    unsigned long long d1 = __hip_atomic_load(hs + 1, __ATOMIC_RELAXED, __HIP_MEMORY_SCOPE_AGENT);
    _Float16 hh[8];
    __builtin_memcpy(&hh[0], &d0, 8);
    __builtin_memcpy(&hh[4], &d1, 8);
    int jbase = kt * 32 + qa * 8;
    #pragma unroll
    for (int jj = 0; jj < 8; ++jj) {
      float hv = (float)hh[jj];
      const float* wr = Wph + (jbase + jj) * NCLS;
      #pragma unroll
      for (int k2 = 0; k2 < NCLS; ++k2) pc[k2] = fmaf(hv, wr[k2], pc[k2]);
    }
    #pragma unroll
    for (int off = 32; off > 0; off >>= 1) {
      #pragma unroll
      for (int k2 = 0; k2 < NCLS; ++k2) pc[k2] += __shfl_down(pc[k2], off);
    }
    if (lane == 0) {
      float mx = -1e30f;
      #pragma unroll
      for (int k2 = 0; k2 < NCLS; ++k2) { pc[k2] += b_p[k2]; mx = fmaxf(mx, pc[k2]); }
      float se = 0.f;
      #pragma unroll
      for (int k2 = 0; k2 < NCLS; ++k2) se += __expf(pc[k2] - mx);
      float ls = mx + __logf(se);
      int b = grp * BPG + cu;
      #pragma unroll
      for (int k2 = 0; k2 < NCLS; ++k2) out[b * NCLS + k2] = pc[k2] - ls;
    }
  }
}

extern "C" void kernel_launch(void* const* d_in, const int* in_sizes, int n_in,
                              void* d_out, int out_size, void* d_ws, size_t ws_size,
                              hipStream_t stream) {
  (void)in_sizes; (void)n_in; (void)out_size; (void)ws_size;
  const int*   x   = (const int*)d_in[0];
  const float* emb = (const float*)d_in[1];
  const float* Wgx = (const float*)d_in[2];
  const float* Wgh = (const float*)d_in[3];
  const float* bg  = (const float*)d_in[4];
  const float* Wix = (const float*)d_in[5];
  const float* Wih = (const float*)d_in[6];
  const float* bi  = (const float*)d_in[7];
  const float* Wfx = (const float*)d_in[8];
  const float* Wfh = (const float*)d_in[9];
  const float* bfv = (const float*)d_in[10];
  const float* Wox = (const float*)d_in[11];
  const float* Woh = (const float*)d_in[12];
  const float* bo  = (const float*)d_in[13];
  const float* Wph = (const float*)d_in[14];
  const float* bp  = (const float*)d_in[15];
  float* out = (float*)d_out;

  unsigned* tags = (unsigned*)d_ws;                        // 4 KB, zeroed per launch
  _Float16* hbuf = (_Float16*)((char*)d_ws + 8192);        // 768 KB h triple-buffer

  hipMemsetAsync(d_ws, 0, 4096, stream);                   // reset tags
  lstm_fused<<<dim3(NGRP * GSIZE), dim3(NTHR), 0, stream>>>(
      x, emb, Wgx, Wgh, bg, Wix, Wih, bi, Wfx, Wfh, bfv,
      Wox, Woh, bo, Wph, bp, out, tags, hbuf);
}

// Round 9
// 3435.077 us; speedup vs baseline: 2.4817x; 2.4817x over previous
//
#include <hip/hip_runtime.h>

// LSTM fused persistent kernel for MI355X — round 9.
// Composition of only proven-passing pieces (R1 protocol shape + R4 publish):
// 16 groups x 16 CUs; CU owns 32 hidden units (128 gate-cols), Wh fp16 in VGPRs.
// Per step: all-wave stage-in (sc1 loads) | barrier | MFMA | NL | per-wave 256B
// direct publish (sc1 stores) | barrier (drains stores) | wave0: one release
// flag per CU + sleepy poll of the group's 16 flags | barrier.
// No threadfence, no XCD swizzle, double-buffered global h (R1 safety proof).

typedef __attribute__((ext_vector_type(8))) _Float16 f16x8;
typedef __attribute__((ext_vector_type(4))) float f32x4;

#define NTHR 256
constexpr int T_LEN = 512, EMB = 1024, HID = 512, NCLS = 10;
constexpr int GSIZE = 16;   // CUs per group
constexpr int NGRP  = 16;   // groups
constexpr int BPG   = 16;   // batches per group
constexpr int UPC   = 32;   // hidden units per CU
constexpr int COLS_PC = 128;
constexpr int NKT = 16;     // K tiles of 32 (HID=512)

__device__ __forceinline__ float sigmf(float x)    { return 1.f / (1.f + __expf(-x)); }
__device__ __forceinline__ float tanhfast(float x) { return 1.f - 2.f / (__expf(2.f * x) + 1.f); }

__global__ __launch_bounds__(NTHR, 1) void lstm_fused(
    const int* __restrict__ xtok, const float* __restrict__ emb,
    const float* __restrict__ Wgx, const float* __restrict__ Wgh, const float* __restrict__ b_g,
    const float* __restrict__ Wix, const float* __restrict__ Wih, const float* __restrict__ b_i,
    const float* __restrict__ Wfx, const float* __restrict__ Wfh, const float* __restrict__ b_f,
    const float* __restrict__ Wox, const float* __restrict__ Woh, const float* __restrict__ b_o,
    const float* __restrict__ Wph, const float* __restrict__ b_p,
    float* __restrict__ out, unsigned* __restrict__ tags, _Float16* __restrict__ hbuf)
{
  const int tid  = threadIdx.x;
  const int wv   = tid >> 6;     // wave 0..3
  const int lane = tid & 63;
  const int q    = lane >> 4;    // lane quarter
  const int c    = lane & 15;
  const int wg   = blockIdx.x;
  const int grp  = wg >> 4;
  const int cu   = wg & 15;

  __shared__ __align__(16) _Float16 h_lds[2][BPG * HID];  // 2 x 16 KB, chunk-major
  __shared__ __align__(16) _Float16 hstw[4][128];         // per-wave pack staging
  __shared__ unsigned char xl[BPG][T_LEN];                // 8 KB packed tokens
  __shared__ float projl[3][COLS_PC];                     // 1.5 KB
  __shared__ float projp[3][COLS_PC];                     // 1.5 KB partials

  // ---- pack this group's tokens into LDS (u8)
  for (int idx = tid; idx < BPG * T_LEN; idx += NTHR) {
    int bl = idx >> 9, tt = idx & (T_LEN - 1);
    xl[bl][tt] = (unsigned char)xtok[(grp * BPG + bl) * T_LEN + tt];
  }

  // ---- proj[v][cc] = b_gate[j] + emb[v] . Wx[:,gate,j], split over 2 halves of e
  {
    int cc = tid & 127, half = tid >> 7;
    int w2 = cc >> 5, nt = (cc >> 4) & 1, c2 = cc & 15;
    int gate = nt * 2 + (c2 >> 3);
    int j = cu * UPC + w2 * 8 + (c2 & 7);
    const float* Wx = gate == 0 ? Wgx : gate == 1 ? Wix : gate == 2 ? Wfx : Wox;
    const float* bb = gate == 0 ? b_g : gate == 1 ? b_i : gate == 2 ? b_f : b_o;
    int e0 = half * (EMB / 2);
    for (int v = 0; v < 3; ++v) {
      float s = half ? 0.f : bb[j];
      const float* er = emb + v * EMB + e0;
      const float* wp = Wx + e0 * HID + j;
      #pragma unroll 4
      for (int e = 0; e < EMB / 2; ++e) s = fmaf(er[e], wp[e * HID], s);
      (half ? projp : projl)[v][cc] = s;
    }
  }
  __syncthreads();
  for (int idx = tid; idx < 3 * COLS_PC; idx += NTHR) {
    int v = idx >> 7, cc = idx & 127;
    projl[v][cc] += projp[v][cc];
  }

  // ---- Wh B-fragments into registers (fp32 -> fp16), kept for all 512 steps.
  // (q, jj) -> k = 8q + jj, applied identically to A and B (HW perm cancels).
  f16x8 Bf[2][NKT];
  {
    int g0 = c >> 3;
    int j = cu * UPC + wv * 8 + (c & 7);
    #pragma unroll
    for (int nt = 0; nt < 2; ++nt) {
      int gate = nt * 2 + g0;
      const float* W = gate == 0 ? Wgh : gate == 1 ? Wih : gate == 2 ? Wfh : Woh;
      #pragma unroll
      for (int kt = 0; kt < NKT; ++kt) {
        f16x8 tmp;
        #pragma unroll
        for (int jj = 0; jj < 8; ++jj)
          tmp[jj] = (_Float16)W[(kt * 32 + q * 8 + jj) * HID + j];
        Bf[nt][kt] = tmp;
      }
    }
  }

  float cst[4] = {0.f, 0.f, 0.f, 0.f};     // c-state, rows q*4+r
  unsigned* tg = tags + grp * 16;          // one flag per CU
  unsigned* hb32 = (unsigned*)hbuf;
  unsigned long long* hb64 = (unsigned long long*)hbuf;
  const int gq2 = grp * 4096;              // group base, qwords (2 bufs x 2048)
  const int gd2 = grp * 8192;              // group base, dwords
  __syncthreads();

  for (int t = 0; t < T_LEN; ++t) {
    const int pl = t & 1;
    if (t > 0) {
      // ---- stage chunks kt = wv*4 .. wv*4+3 into LDS (chunk layout == A-frag)
      const int pbase = gq2 + pl * 2048;
      #pragma unroll
      for (int i = 0; i < 4; ++i) {
        int kt = wv * 4 + i;
        int o = pbase + kt * 128 + lane * 2;
        unsigned long long d0 = __hip_atomic_load(hb64 + o,     __ATOMIC_RELAXED, __HIP_MEMORY_SCOPE_AGENT);
        unsigned long long d1 = __hip_atomic_load(hb64 + o + 1, __ATOMIC_RELAXED, __HIP_MEMORY_SCOPE_AGENT);
        unsigned long long* dl = (unsigned long long*)&h_lds[pl][kt * 512 + lane * 8];
        dl[0] = d0; dl[1] = d1;
      }
    }
    __syncthreads();

    // ---- gates tile: 16 batches x 32 cols per wave (2 n-tiles), K=512
    f32x4 acc0 = {0.f, 0.f, 0.f, 0.f}, acc1 = {0.f, 0.f, 0.f, 0.f};
    if (t > 0) {
      const _Float16* hp = h_lds[pl];
      #pragma unroll
      for (int kt = 0; kt < NKT; ++kt) {
        f16x8 a = *(const f16x8*)(hp + kt * 512 + lane * 8);
        acc0 = __builtin_amdgcn_mfma_f32_16x16x32_f16(a, Bf[0][kt], acc0, 0, 0, 0);
        acc1 = __builtin_amdgcn_mfma_f32_16x16x32_f16(a, Bf[1][kt], acc1, 0, 0, 0);
      }
    }

    // ---- nonlinearity + state update. C/D layout: col=lane&15, row=4q+reg.
    bool lo = (c < 8);
    #pragma unroll
    for (int r = 0; r < 4; ++r) {
      int bl = q * 4 + r;                     // batch row in tile
      int v = xl[bl][t];
      float p0 = acc0[r] + projl[v][wv * 32 + c];
      float p1 = acc1[r] + projl[v][wv * 32 + 16 + c];
      float p0x = __shfl_xor(p0, 8);
      float p1x = __shfl_xor(p1, 8);
      float gg = lo ? p0  : p0x;
      float ii = lo ? p0x : p0;
      float ff = lo ? p1  : p1x;
      float oo = lo ? p1x : p1;
      gg = tanhfast(gg); ii = sigmf(ii); ff = sigmf(ff); oo = sigmf(oo);
      float cn = fmaf(cst[r], ff, gg * ii);
      cst[r] = cn;
      float hv = tanhfast(cn) * oo;
      if (lo) hstw[wv][bl * 8 + c] = (_Float16)hv;   // same-wave staging (no barrier)
    }

    // ---- per-wave direct publish of this wave's 256B slice into buffer (t+1)&1
    {
      unsigned pub = ((const unsigned*)&hstw[wv][0])[lane];
      int po = gd2 + ((t + 1) & 1) * 4096 + cu * 256 + wv * 64 + lane;
      __hip_atomic_store(hb32 + po, pub, __ATOMIC_RELAXED, __HIP_MEMORY_SCOPE_AGENT);
    }
    __syncthreads();   // drains every wave's publish stores (vmcnt(0) before s_barrier)

    // ---- wave0: single release flag per CU, then sleepy poll of 16 flags
    if (wv == 0) {
      if (lane == 0)
        __hip_atomic_store(tg + cu, (unsigned)(t + 1), __ATOMIC_RELEASE, __HIP_MEMORY_SCOPE_AGENT);
      const unsigned tc = (unsigned)(t + 1);
      for (;;) {
        unsigned v = (lane < 16)
            ? __hip_atomic_load(tg + lane, __ATOMIC_RELAXED, __HIP_MEMORY_SCOPE_AGENT)
            : tc;
        if (__all((int)(v >= tc))) break;
        __builtin_amdgcn_s_sleep(1);
      }
      asm volatile("" ::: "memory");
    }
    __syncthreads();
  }

  // ---- epilogue: loop's final poll already synced h_512 (buffer 0).
  // p = h_T @ W_ph + b_p ; log_softmax for batch grp*16+cu.
  if (wv == 0) {
    float pc[NCLS];
    #pragma unroll
    for (int k2 = 0; k2 < NCLS; ++k2) pc[k2] = 0.f;
    int kt = lane >> 2, qa = lane & 3;        // each lane: 8 consecutive j
    const unsigned long long* hs = hb64 + gq2 + (kt * 64 + qa * 16 + cu) * 2;
    unsigned long long d0 = __hip_atomic_load(hs,     __ATOMIC_RELAXED, __HIP_MEMORY_SCOPE_AGENT);
    unsigned long long d1 = __hip_atomic_load(hs + 1, __ATOMIC_RELAXED, __HIP_MEMORY_SCOPE_AGENT);
    _Float16 hh[8];
    __builtin_memcpy(&hh[0], &d0, 8);
    __builtin_memcpy(&hh[4], &d1, 8);
    int jbase = kt * 32 + qa * 8;
    #pragma unroll
    for (int jj = 0; jj < 8; ++jj) {
      float hv = (float)hh[jj];
      const float* wr = Wph + (jbase + jj) * NCLS;
      #pragma unroll
      for (int k2 = 0; k2 < NCLS; ++k2) pc[k2] = fmaf(hv, wr[k2], pc[k2]);
    }
    #pragma unroll
    for (int off = 32; off > 0; off >>= 1) {
      #pragma unroll
      for (int k2 = 0; k2 < NCLS; ++k2) pc[k2] += __shfl_down(pc[k2], off);
    }
    if (lane == 0) {
      float mx = -1e30f;
      #pragma unroll
      for (int k2 = 0; k2 < NCLS; ++k2) { pc[k2] += b_p[k2]; mx = fmaxf(mx, pc[k2]); }
      float se = 0.f;
      #pragma unroll
      for (int k2 = 0; k2 < NCLS; ++k2) se += __expf(pc[k2] - mx);
      float ls = mx + __logf(se);
      int b = grp * BPG + cu;
      #pragma unroll
      for (int k2 = 0; k2 < NCLS; ++k2) out[b * NCLS + k2] = pc[k2] - ls;
    }
  }
}

extern "C" void kernel_launch(void* const* d_in, const int* in_sizes, int n_in,
                              void* d_out, int out_size, void* d_ws, size_t ws_size,
                              hipStream_t stream) {
  (void)in_sizes; (void)n_in; (void)out_size; (void)ws_size;
  const int*   x   = (const int*)d_in[0];
  const float* emb = (const float*)d_in[1];
  const float* Wgx = (const float*)d_in[2];
  const float* Wgh = (const float*)d_in[3];
  const float* bg  = (const float*)d_in[4];
  const float* Wix = (const float*)d_in[5];
  const float* Wih = (const float*)d_in[6];
  const float* bi  = (const float*)d_in[7];
  const float* Wfx = (const float*)d_in[8];
  const float* Wfh = (const float*)d_in[9];
  const float* bfv = (const float*)d_in[10];
  const float* Wox = (const float*)d_in[11];
  const float* Woh = (const float*)d_in[12];
  const float* bo  = (const float*)d_in[13];
  const float* Wph = (const float*)d_in[14];
  const float* bp  = (const float*)d_in[15];
  float* out = (float*)d_out;

  unsigned* tags = (unsigned*)d_ws;                        // 1 KB, zeroed per launch
  _Float16* hbuf = (_Float16*)((char*)d_ws + 8192);        // 512 KB h double-buffer

  (void)hipMemsetAsync(d_ws, 0, 1024, stream);             // reset flags
  lstm_fused<<<dim3(NGRP * GSIZE), dim3(NTHR), 0, stream>>>(
      x, emb, Wgx, Wgh, bg, Wix, Wih, bi, Wfx, Wfh, bfv,
      Wox, Woh, bo, Wph, bp, out, tags, hbuf);
}

// Round 10
// 1867.913 us; speedup vs baseline: 4.5639x; 1.8390x over previous
//
#include <hip/hip_runtime.h>

// LSTM fused persistent kernel for MI355X — round 10: single-hop tagged-data exchange.
// 16 groups x 16 CUs; CU owns 32 hidden units; Wh fp16 in VGPRs (proven blocks).
// h published as 16B units {4 fp16, tag, pad} via single dwordx4 store (atomic
// visibility). Consumers poll their own units (narrow, sleepy) — data arrives
// with the tag. No flags, no drain barrier, ONE __syncthreads per step.
// Triple-buffered global h (WAR by poll transitivity), double-buffered LDS.

typedef __attribute__((ext_vector_type(8))) _Float16 f16x8;
typedef __attribute__((ext_vector_type(4))) float f32x4;
typedef __attribute__((ext_vector_type(4))) unsigned u32x4;
typedef __attribute__((ext_vector_type(2))) unsigned u32x2;

#define NTHR 256
constexpr int T_LEN = 512, EMB = 1024, HID = 512, NCLS = 10;
constexpr int GSIZE = 16;   // CUs per group
constexpr int NGRP  = 16;   // groups
constexpr int BPG   = 16;   // batches per group
constexpr int UPC   = 32;   // hidden units per CU
constexpr int COLS_PC = 128;
constexpr int NKT = 16;     // K tiles of 32 (HID=512)
constexpr int GUNITS  = GSIZE * 128;   // 16B-units per buffer per group (2048)
constexpr int GSTRIDE = 3 * GUNITS;    // units per group (3 buffers)

__device__ __forceinline__ float sigmf(float x)    { return 1.f / (1.f + __expf(-x)); }
__device__ __forceinline__ float tanhfast(float x) { return 1.f - 2.f / (__expf(2.f * x) + 1.f); }

// issue two 16B loads (base, base+16B), no wait — caller drains vmcnt
__device__ __forceinline__ void ld_pair(const u32x4* p, u32x4& a, u32x4& b) {
  asm volatile("global_load_dwordx4 %0, %2, off sc0 sc1\n\t"
               "global_load_dwordx4 %1, %2, off offset:16 sc0 sc1"
               : "=&v"(a), "=&v"(b) : "v"(p) : "memory");
}
__device__ __forceinline__ void wait_vm0() {
  asm volatile("s_waitcnt vmcnt(0)" ::: "memory");
  __builtin_amdgcn_sched_barrier(0);          // rule #18: pin consumers after waitcnt
}
__device__ __forceinline__ void st16(u32x4* p, u32x4 v) {
  asm volatile("global_store_dwordx4 %0, %1, off sc0 sc1" :: "v"(p), "v"(v) : "memory");
}

__global__ __launch_bounds__(NTHR, 1) void lstm_fused(
    const int* __restrict__ xtok, const float* __restrict__ emb,
    const float* __restrict__ Wgx, const float* __restrict__ Wgh, const float* __restrict__ b_g,
    const float* __restrict__ Wix, const float* __restrict__ Wih, const float* __restrict__ b_i,
    const float* __restrict__ Wfx, const float* __restrict__ Wfh, const float* __restrict__ b_f,
    const float* __restrict__ Wox, const float* __restrict__ Woh, const float* __restrict__ b_o,
    const float* __restrict__ Wph, const float* __restrict__ b_p,
    float* __restrict__ out, u32x4* __restrict__ gb)
{
  const int tid  = threadIdx.x;
  const int wv   = tid >> 6;     // wave 0..3
  const int lane = tid & 63;
  const int q    = lane >> 4;    // lane quarter
  const int c    = lane & 15;
  const int wg   = blockIdx.x;
  const int grp  = wg >> 4;
  const int cu   = wg & 15;

  __shared__ __align__(16) _Float16 h_lds[2][BPG * HID];  // 2 x 16 KB, chunk-major
  __shared__ __align__(16) _Float16 hstw[4][128];         // per-wave pack staging
  __shared__ unsigned char xl[BPG][T_LEN];                // 8 KB packed tokens
  __shared__ float projl[3][COLS_PC];                     // 1.5 KB
  __shared__ float projp[3][COLS_PC];                     // 1.5 KB partials

  // ---- pack this group's tokens into LDS (u8)
  for (int idx = tid; idx < BPG * T_LEN; idx += NTHR) {
    int bl = idx >> 9, tt = idx & (T_LEN - 1);
    xl[bl][tt] = (unsigned char)xtok[(grp * BPG + bl) * T_LEN + tt];
  }

  // ---- proj[v][cc] = b_gate[j] + emb[v] . Wx[:,gate,j], split over 2 halves of e
  {
    int cc = tid & 127, half = tid >> 7;
    int w2 = cc >> 5, nt = (cc >> 4) & 1, c2 = cc & 15;
    int gate = nt * 2 + (c2 >> 3);
    int j = cu * UPC + w2 * 8 + (c2 & 7);
    const float* Wx = gate == 0 ? Wgx : gate == 1 ? Wix : gate == 2 ? Wfx : Wox;
    const float* bb = gate == 0 ? b_g : gate == 1 ? b_i : gate == 2 ? b_f : b_o;
    int e0 = half * (EMB / 2);
    for (int v = 0; v < 3; ++v) {
      float s = half ? 0.f : bb[j];
      const float* er = emb + v * EMB + e0;
      const float* wp = Wx + e0 * HID + j;
      #pragma unroll 4
      for (int e = 0; e < EMB / 2; ++e) s = fmaf(er[e], wp[e * HID], s);
      (half ? projp : projl)[v][cc] = s;
    }
  }
  __syncthreads();
  for (int idx = tid; idx < 3 * COLS_PC; idx += NTHR) {
    int v = idx >> 7, cc = idx & 127;
    projl[v][cc] += projp[v][cc];
  }

  // ---- Wh B-fragments into registers (fp32 -> fp16), kept for all 512 steps.
  // (q, jj) -> k = 8q + jj, applied identically to A and B (HW perm cancels).
  f16x8 Bf[2][NKT];
  {
    int g0 = c >> 3;
    int j = cu * UPC + wv * 8 + (c & 7);
    #pragma unroll
    for (int nt = 0; nt < 2; ++nt) {
      int gate = nt * 2 + g0;
      const float* W = gate == 0 ? Wgh : gate == 1 ? Wih : gate == 2 ? Wfh : Woh;
      #pragma unroll
      for (int kt = 0; kt < NKT; ++kt) {
        f16x8 tmp;
        #pragma unroll
        for (int jj = 0; jj < 8; ++jj)
          tmp[jj] = (_Float16)W[(kt * 32 + q * 8 + jj) * HID + j];
        Bf[nt][kt] = tmp;
      }
    }
  }

  float cst[4] = {0.f, 0.f, 0.f, 0.f};     // c-state, rows q*4+r
  u32x4* ug = gb + grp * GSTRIDE;          // this group's 3 buffers (units)
  int br = 0;                              // read buffer == t % 3
  __syncthreads();

  for (int t = 0; t < T_LEN; ++t) {
    const int pl = t & 1;
    if (t > 0) {
      // ---- narrow tagged-data poll: this wave's 4 chunks, 2 units per lane.
      // Tag==t is embedded in each 16B unit (atomic dwordx4 visibility).
      const unsigned tagv = (unsigned)t;
      const u32x4* rb = ug + br * GUNITS;
      u32x4 ua[4], ubv[4];
      for (;;) {
        #pragma unroll
        for (int i = 0; i < 4; ++i)
          ld_pair(rb + (wv * 4 + i) * 128 + 2 * lane, ua[i], ubv[i]);
        wait_vm0();
        bool ok = true;
        #pragma unroll
        for (int i = 0; i < 4; ++i)
          ok = ok && (ua[i][2] == tagv) && (ubv[i][2] == tagv);
        if (__all((int)ok)) break;
        __builtin_amdgcn_s_sleep(1);
      }
      // ---- stage into LDS (identical A-frag layout: fp16 [lane*8, +8) of chunk)
      #pragma unroll
      for (int i = 0; i < 4; ++i) {
        int kt = wv * 4 + i;
        u32x2 lo = {ua[i][0], ua[i][1]};
        u32x2 hi = {ubv[i][0], ubv[i][1]};
        *(u32x2*)&h_lds[pl][kt * 512 + lane * 8]     = lo;
        *(u32x2*)&h_lds[pl][kt * 512 + lane * 8 + 4] = hi;
      }
    }
    __syncthreads();   // the ONLY barrier per step

    // ---- gates tile: 16 batches x 32 cols per wave (2 n-tiles), K=512
    f32x4 acc0 = {0.f, 0.f, 0.f, 0.f}, acc1 = {0.f, 0.f, 0.f, 0.f};
    if (t > 0) {
      const _Float16* hp = h_lds[pl];
      #pragma unroll
      for (int kt = 0; kt < NKT; ++kt) {
        f16x8 a = *(const f16x8*)(hp + kt * 512 + lane * 8);
        acc0 = __builtin_amdgcn_mfma_f32_16x16x32_f16(a, Bf[0][kt], acc0, 0, 0, 0);
        acc1 = __builtin_amdgcn_mfma_f32_16x16x32_f16(a, Bf[1][kt], acc1, 0, 0, 0);
      }
    }

    // ---- nonlinearity + state update. C/D layout: col=lane&15, row=4q+reg.
    bool lo8 = (c < 8);
    #pragma unroll
    for (int r = 0; r < 4; ++r) {
      int bl = q * 4 + r;                     // batch row in tile
      int v = xl[bl][t];
      float p0 = acc0[r] + projl[v][wv * 32 + c];
      float p1 = acc1[r] + projl[v][wv * 32 + 16 + c];
      float p0x = __shfl_xor(p0, 8);
      float p1x = __shfl_xor(p1, 8);
      float gg = lo8 ? p0  : p0x;
      float ii = lo8 ? p0x : p0;
      float ff = lo8 ? p1  : p1x;
      float oo = lo8 ? p1x : p1;
      gg = tanhfast(gg); ii = sigmf(ii); ff = sigmf(ff); oo = sigmf(oo);
      float cn = fmaf(cst[r], ff, gg * ii);
      cst[r] = cn;
      float hv = tanhfast(cn) * oo;
      if (lo8) hstw[wv][bl * 8 + c] = (_Float16)hv;   // same-wave staging (proven)
    }

    // ---- publish: 32 units of {4 fp16, tag=t+1, 0} into buffer (t+1)%3
    int bw = (br + 1 == 3) ? 0 : br + 1;
    if (lane < 32) {
      const unsigned* hw = (const unsigned*)&hstw[wv][0];
      u32x4 pv = {hw[2 * lane], hw[2 * lane + 1], (unsigned)(t + 1), 0u};
      st16(ug + bw * GUNITS + cu * 128 + wv * 32 + lane, pv);
    }
    br = bw;
  }

  // ---- epilogue: poll final units (tag == 512, buffer 512%3 == 2), then
  // p = h_T @ W_ph + b_p ; log_softmax for batch grp*16+cu.
  if (wv == 0) {
    const u32x4* rb = ug + 2 * GUNITS;
    int kt = lane >> 2, qa = lane & 3;        // each lane: 8 consecutive j
    const u32x4* p = rb + kt * 128 + 2 * (qa * 16 + cu);
    u32x4 a, b;
    for (;;) {
      ld_pair(p, a, b);
      wait_vm0();
      bool ok = (a[2] == (unsigned)T_LEN) && (b[2] == (unsigned)T_LEN);
      if (__all((int)ok)) break;
      __builtin_amdgcn_s_sleep(1);
    }
    _Float16 hh[8];
    u32x2 lo2 = {a[0], a[1]}, hi2 = {b[0], b[1]};
    __builtin_memcpy(&hh[0], &lo2, 8);
    __builtin_memcpy(&hh[4], &hi2, 8);
    float pc[NCLS];
    #pragma unroll
    for (int k2 = 0; k2 < NCLS; ++k2) pc[k2] = 0.f;
    int jbase = kt * 32 + qa * 8;
    #pragma unroll
    for (int jj = 0; jj < 8; ++jj) {
      float hv = (float)hh[jj];
      const float* wr = Wph + (jbase + jj) * NCLS;
      #pragma unroll
      for (int k2 = 0; k2 < NCLS; ++k2) pc[k2] = fmaf(hv, wr[k2], pc[k2]);
    }
    #pragma unroll
    for (int off = 32; off > 0; off >>= 1) {
      #pragma unroll
      for (int k2 = 0; k2 < NCLS; ++k2) pc[k2] += __shfl_down(pc[k2], off);
    }
    if (lane == 0) {
      float mx = -1e30f;
      #pragma unroll
      for (int k2 = 0; k2 < NCLS; ++k2) { pc[k2] += b_p[k2]; mx = fmaxf(mx, pc[k2]); }
      float se = 0.f;
      #pragma unroll
      for (int k2 = 0; k2 < NCLS; ++k2) se += __expf(pc[k2] - mx);
      float ls = mx + __logf(se);
      int b2 = grp * BPG + cu;
      #pragma unroll
      for (int k2 = 0; k2 < NCLS; ++k2) out[b2 * NCLS + k2] = pc[k2] - ls;
    }
  }
}

extern "C" void kernel_launch(void* const* d_in, const int* in_sizes, int n_in,
                              void* d_out, int out_size, void* d_ws, size_t ws_size,
                              hipStream_t stream) {
  (void)in_sizes; (void)n_in; (void)out_size; (void)ws_size;
  const int*   x   = (const int*)d_in[0];
  const float* emb = (const float*)d_in[1];
  const float* Wgx = (const float*)d_in[2];
  const float* Wgh = (const float*)d_in[3];
  const float* bg  = (const float*)d_in[4];
  const float* Wix = (const float*)d_in[5];
  const float* Wih = (const float*)d_in[6];
  const float* bi  = (const float*)d_in[7];
  const float* Wfx = (const float*)d_in[8];
  const float* Wfh = (const float*)d_in[9];
  const float* bfv = (const float*)d_in[10];
  const float* Wox = (const float*)d_in[11];
  const float* Woh = (const float*)d_in[12];
  const float* bo  = (const float*)d_in[13];
  const float* Wph = (const float*)d_in[14];
  const float* bp  = (const float*)d_in[15];
  float* out = (float*)d_out;

  // 16 groups x 3 buffers x 2048 units x 16B = 1.5 MB, tags cleared per launch
  (void)hipMemsetAsync(d_ws, 0, (size_t)NGRP * GSTRIDE * 16, stream);
  lstm_fused<<<dim3(NGRP * GSIZE), dim3(NTHR), 0, stream>>>(
      x, emb, Wgx, Wgh, bg, Wix, Wih, bi, Wfx, Wfh, bfv,
      Wox, Woh, bo, Wph, bp, out, (u32x4*)d_ws);
}